// Round 1
// baseline (246.965 us; speedup 1.0000x reference)
//
#include <hip/hip_runtime.h>

#define N_ROWS  4096
#define IN_DIM  256
#define OUT_DIM 256
#define ROWS_PER_BLOCK 4   // one row per wave (4 waves / block)

// ---------------------------------------------------------------------------
// Kernel 1: precompute exp(log_sigma) for weights and biases into workspace.
// 65536 + 256 elements; trivially memory-bound, ~2 us.
// ---------------------------------------------------------------------------
__global__ void bayes_exp_kernel(const float* __restrict__ logw,
                                 const float* __restrict__ logb,
                                 float* __restrict__ sw,
                                 float* __restrict__ sb) {
    int idx = blockIdx.x * blockDim.x + threadIdx.x;
    if (idx < IN_DIM * OUT_DIM) sw[idx] = __expf(logw[idx]);
    if (idx < OUT_DIM)          sb[idx] = __expf(logb[idx]);
}

// ---------------------------------------------------------------------------
// Kernel 2: main batched matvec with reparameterized weights.
// Block = 256 threads = 4 waves; wave w handles row n0+w; lane owns 4 outputs.
// eps_w is streamed once (coalesced float4); w1 / sw rows hit L2.
// PRE=true: sw/sb hold exp() precomputed. PRE=false: they hold the logs and
// we exp() inline (fallback when ws_size is too small).
// ---------------------------------------------------------------------------
template <bool PRE>
__global__ __launch_bounds__(256) void bayes_main_kernel(
    const float* __restrict__ x,      // [N, IN]
    const float* __restrict__ eps_w,  // [N, IN, OUT]
    const float* __restrict__ eps_b,  // [N, OUT]
    const float* __restrict__ w1,     // [IN, OUT]
    const float* __restrict__ swl,    // [IN, OUT]  exp(logw2) or logw2
    const float* __restrict__ b1,     // [OUT]
    const float* __restrict__ sbl,    // [OUT]      exp(logb2) or logb2
    float* __restrict__ out)          // [N, OUT]
{
    __shared__ float xs[ROWS_PER_BLOCK * IN_DIM];

    const int tid = threadIdx.x;
    const int n0  = blockIdx.x * ROWS_PER_BLOCK;

    // Cooperative load of 4 x-rows (1024 contiguous floats) into LDS.
    ((float4*)xs)[tid] = ((const float4*)(x + (size_t)n0 * IN_DIM))[tid];
    __syncthreads();

    const int row = tid >> 6;     // wave index == row within block
    const int o4  = tid & 63;     // float4 column index (64 * 4 = 256 outputs)
    const int n   = n0 + row;

    const float4* e4 = (const float4*)(eps_w + (size_t)n * IN_DIM * OUT_DIM) + o4;
    const float4* w4 = (const float4*)w1  + o4;
    const float4* s4 = (const float4*)swl + o4;
    const int     ld = OUT_DIM / 4;   // float4 stride per i

    float4 acc = make_float4(0.f, 0.f, 0.f, 0.f);

    #pragma unroll 4
    for (int i = 0; i < IN_DIM; ++i) {
        const float  xv = xs[row * IN_DIM + i];   // wave-uniform LDS broadcast
        const float4 e  = e4[i * ld];
        const float4 w  = w4[i * ld];
        float4 s        = s4[i * ld];
        if (!PRE) {
            s.x = __expf(s.x); s.y = __expf(s.y);
            s.z = __expf(s.z); s.w = __expf(s.w);
        }
        acc.x = fmaf(xv, fmaf(s.x, e.x, w.x), acc.x);
        acc.y = fmaf(xv, fmaf(s.y, e.y, w.y), acc.y);
        acc.z = fmaf(xv, fmaf(s.z, e.z, w.z), acc.z);
        acc.w = fmaf(xv, fmaf(s.w, e.w, w.w), acc.w);
    }

    // Epilogue: bias + sigma_b * eps_b
    const float4 eb = ((const float4*)(eps_b + (size_t)n * OUT_DIM))[o4];
    const float4 b  = ((const float4*)b1)[o4];
    float4 sb       = ((const float4*)sbl)[o4];
    if (!PRE) {
        sb.x = __expf(sb.x); sb.y = __expf(sb.y);
        sb.z = __expf(sb.z); sb.w = __expf(sb.w);
    }

    float4 res;
    res.x = acc.x + fmaf(sb.x, eb.x, b.x);
    res.y = acc.y + fmaf(sb.y, eb.y, b.y);
    res.z = acc.z + fmaf(sb.z, eb.z, b.z);
    res.w = acc.w + fmaf(sb.w, eb.w, b.w);

    ((float4*)(out + (size_t)n * OUT_DIM))[o4] = res;
}

extern "C" void kernel_launch(void* const* d_in, const int* in_sizes, int n_in,
                              void* d_out, int out_size, void* d_ws, size_t ws_size,
                              hipStream_t stream) {
    const float* x     = (const float*)d_in[0];
    const float* eps_w = (const float*)d_in[1];
    const float* eps_b = (const float*)d_in[2];
    const float* w1    = (const float*)d_in[3];
    const float* logw2 = (const float*)d_in[4];
    const float* b1    = (const float*)d_in[5];
    const float* logb2 = (const float*)d_in[6];
    float* out = (float*)d_out;

    const size_t need = (size_t)(IN_DIM * OUT_DIM + OUT_DIM) * sizeof(float);
    const int grid = N_ROWS / ROWS_PER_BLOCK;   // 1024 blocks

    if (ws_size >= need) {
        float* sw = (float*)d_ws;
        float* sb = sw + IN_DIM * OUT_DIM;
        bayes_exp_kernel<<<(IN_DIM * OUT_DIM + 255) / 256, 256, 0, stream>>>(
            logw2, logb2, sw, sb);
        bayes_main_kernel<true><<<grid, 256, 0, stream>>>(
            x, eps_w, eps_b, w1, sw, b1, sb, out);
    } else {
        bayes_main_kernel<false><<<grid, 256, 0, stream>>>(
            x, eps_w, eps_b, w1, logw2, b1, logb2, out);
    }
}

// Round 2
// 202.157 us; speedup vs baseline: 1.2217x; 1.2217x over previous
//
#include <hip/hip_runtime.h>

#define N_ROWS  4096
#define IN_DIM  256
#define OUT_DIM 256
#define R       8            // rows per block (one row per wave)
#define T       (R * 64)     // 512 threads
#define NT      (T)
#define TI      32           // i-tile staged in LDS
#define NT4     (TI * OUT_DIM / 4)   // float4s per staged array tile = 2048

// ---------------------------------------------------------------------------
// Kernel 1: precompute exp(log_sigma) for weights and biases into workspace.
// ---------------------------------------------------------------------------
__global__ void bayes_exp_kernel(const float* __restrict__ logw,
                                 const float* __restrict__ logb,
                                 float* __restrict__ sw,
                                 float* __restrict__ sb) {
    int idx = blockIdx.x * blockDim.x + threadIdx.x;
    if (idx < IN_DIM * OUT_DIM) sw[idx] = __expf(logw[idx]);
    if (idx < OUT_DIM)          sb[idx] = __expf(logb[idx]);
}

// ---------------------------------------------------------------------------
// Kernel 2: batched matvec with reparameterized weights.
// Block = 512 threads = 8 waves; wave w owns row n0+w; lane owns 4 outputs.
// w1 / sw are staged tile-by-tile (TI i-values) into LDS: each block reads
// them exactly once from global (vs once per ROW before), removing the
// L2-thrash exposure. eps_w remains a pure sequential float4 HBM stream.
// PRE=false fallback applies expf during staging.
// ---------------------------------------------------------------------------
template <bool PRE>
__global__ __launch_bounds__(512) void bayes_main_kernel(
    const float* __restrict__ x,      // [N, IN]
    const float* __restrict__ eps_w,  // [N, IN, OUT]
    const float* __restrict__ eps_b,  // [N, OUT]
    const float* __restrict__ w1,     // [IN, OUT]
    const float* __restrict__ swl,    // [IN, OUT] exp(logw2) or logw2
    const float* __restrict__ b1,     // [OUT]
    const float* __restrict__ sbl,    // [OUT]     exp(logb2) or logb2
    float* __restrict__ out)          // [N, OUT]
{
    __shared__ float xs[R * IN_DIM];        // 8 KB
    __shared__ float wt[TI * OUT_DIM];      // 32 KB
    __shared__ float st[TI * OUT_DIM];      // 32 KB   -> 72 KB total, 2 blocks/CU

    const int tid = threadIdx.x;
    const int n0  = blockIdx.x * R;

    // Stage x rows (R*IN_DIM = 2048 floats = 512 float4s; one per thread).
    ((float4*)xs)[tid] = ((const float4*)(x + (size_t)n0 * IN_DIM))[tid];

    const int row = tid >> 6;     // wave index == row within block
    const int o4  = tid & 63;     // float4 column index
    const int n   = n0 + row;

    const float4* e4base = (const float4*)(eps_w + (size_t)n * IN_DIM * OUT_DIM) + o4;
    const int     ld4    = OUT_DIM / 4;   // 64

    float4 acc = make_float4(0.f, 0.f, 0.f, 0.f);

    for (int t = 0; t < IN_DIM / TI; ++t) {
        __syncthreads();   // previous tile's readers done (also covers xs at t=0)

        // Cooperatively stage w1/sw tile: TI*OUT_DIM = 8192 floats each.
        {
            const float4* wsrc = (const float4*)(w1  + t * TI * OUT_DIM);
            const float4* ssrc = (const float4*)(swl + t * TI * OUT_DIM);
            float4 wv[4], sv[4];
            #pragma unroll
            for (int k = 0; k < 4; ++k) {
                wv[k] = wsrc[tid + k * NT];
                sv[k] = ssrc[tid + k * NT];
            }
            if (!PRE) {
                #pragma unroll
                for (int k = 0; k < 4; ++k) {
                    sv[k].x = __expf(sv[k].x); sv[k].y = __expf(sv[k].y);
                    sv[k].z = __expf(sv[k].z); sv[k].w = __expf(sv[k].w);
                }
            }
            #pragma unroll
            for (int k = 0; k < 4; ++k) {
                ((float4*)wt)[tid + k * NT] = wv[k];
                ((float4*)st)[tid + k * NT] = sv[k];
            }
        }
        __syncthreads();

        const float4* e4 = e4base + (size_t)t * TI * ld4;
        #pragma unroll 4
        for (int i = 0; i < TI; ++i) {
            const float  xv = xs[row * IN_DIM + t * TI + i];  // wave-uniform broadcast
            const float4 e  = e4[i * ld4];
            const float4 w  = ((const float4*)wt)[i * 64 + o4];
            const float4 s  = ((const float4*)st)[i * 64 + o4];
            acc.x = fmaf(xv, fmaf(s.x, e.x, w.x), acc.x);
            acc.y = fmaf(xv, fmaf(s.y, e.y, w.y), acc.y);
            acc.z = fmaf(xv, fmaf(s.z, e.z, w.z), acc.z);
            acc.w = fmaf(xv, fmaf(s.w, e.w, w.w), acc.w);
        }
    }

    // Epilogue: bias + sigma_b * eps_b
    const float4 eb = ((const float4*)(eps_b + (size_t)n * OUT_DIM))[o4];
    const float4 b  = ((const float4*)b1)[o4];
    float4 sb       = ((const float4*)sbl)[o4];
    if (!PRE) {
        sb.x = __expf(sb.x); sb.y = __expf(sb.y);
        sb.z = __expf(sb.z); sb.w = __expf(sb.w);
    }

    float4 res;
    res.x = acc.x + fmaf(sb.x, eb.x, b.x);
    res.y = acc.y + fmaf(sb.y, eb.y, b.y);
    res.z = acc.z + fmaf(sb.z, eb.z, b.z);
    res.w = acc.w + fmaf(sb.w, eb.w, b.w);

    ((float4*)(out + (size_t)n * OUT_DIM))[o4] = res;
}

extern "C" void kernel_launch(void* const* d_in, const int* in_sizes, int n_in,
                              void* d_out, int out_size, void* d_ws, size_t ws_size,
                              hipStream_t stream) {
    const float* x     = (const float*)d_in[0];
    const float* eps_w = (const float*)d_in[1];
    const float* eps_b = (const float*)d_in[2];
    const float* w1    = (const float*)d_in[3];
    const float* logw2 = (const float*)d_in[4];
    const float* b1    = (const float*)d_in[5];
    const float* logb2 = (const float*)d_in[6];
    float* out = (float*)d_out;

    const size_t need = (size_t)(IN_DIM * OUT_DIM + OUT_DIM) * sizeof(float);
    const int grid = N_ROWS / R;   // 512 blocks

    if (ws_size >= need) {
        float* sw = (float*)d_ws;
        float* sb = sw + IN_DIM * OUT_DIM;
        bayes_exp_kernel<<<(IN_DIM * OUT_DIM + 255) / 256, 256, 0, stream>>>(
            logw2, logb2, sw, sb);
        bayes_main_kernel<true><<<grid, T, 0, stream>>>(
            x, eps_w, eps_b, w1, sw, b1, sb, out);
    } else {
        bayes_main_kernel<false><<<grid, T, 0, stream>>>(
            x, eps_w, eps_b, w1, logw2, b1, logb2, out);
    }
}